// Round 4
// baseline (148.301 us; speedup 1.0000x reference)
//
#include <hip/hip_runtime.h>
#include <cstdint>
#include <cstddef>

#define VOCAB 50000
#define EMBED 256
#define BATCH 16384
#define NSAMP 4096

typedef float f32x4 __attribute__((ext_vector_type(4)));
typedef int   i32x4 __attribute__((ext_vector_type(4)));
typedef int   i32x8 __attribute__((ext_vector_type(8)));

typedef __attribute__((address_space(3))) void lds_void_t;
typedef __attribute__((address_space(1))) void g_void_t;

// ---------- helpers ----------

__device__ __forceinline__ float log_expected_count(int id) {
    float idf = (float)id;
    float p = log1pf(1.0f / (idf + 1.0f)) / logf((float)(VOCAB + 1));
    return __logf(-expm1f((float)NSAMP * log1pf(-p)));
}

// softplus(x) = max(x,0) + log1p(e^{-|x|}); deg-5 minimax (|err|<=1e-5)
__device__ __forceinline__ float softplus_f(float x) {
    float v = __expf(-fabsf(x));
    float p = fmaf(v, 0.03215845f, -0.13606275f);
    p = fmaf(v, p, 0.28947478f);
    p = fmaf(v, p, -0.49190896f);
    p = fmaf(v, p, 0.99949556f);
    return fmaxf(x, 0.0f) + v * p;
}

// pack 4 floats -> 4 fp8 e4m3 bytes (HW cvt, OCP on gfx950)
__device__ __forceinline__ int pk4_fp8(float a, float b, float c, float d) {
    int v = __builtin_amdgcn_cvt_pk_fp8_f32(a, b, 0, false);
    v = __builtin_amdgcn_cvt_pk_fp8_f32(c, d, v, true);
    return v;
}

// Half-split fragment layout for an R x 256 fp8 matrix:
//   offset(r,k) = (r>>4)*4096 + (k>>7)*2048 + ((k>>4)&1)*1024
//               + ((r&15) + ((k>>5)&3)*16)*16 + (k&15)
// => a 128x256 tile's 8 row-groups are one CONTIGUOUS 32 KB block, and a
//    wave frag (group g, k-step s) reads half h at g*4096+s*2048+h*1024+lane*16
//    — the canonical conflict-free lane*16 pattern for both global_load_lds
//    staging (identity copy) and ds_read_b128.

// ---------- kernels ----------

// blocks [0,1024): true logits + E -> fp8 fragment conversion (1 wave = 4 rows)
// blocks [1024,1088): gather W[sids] * 16 -> fp8 fragments + badj
__global__ __launch_bounds__(256) void k_prep(
        const float* __restrict__ E, const int* __restrict__ tgt,
        const int* __restrict__ sids, const float* __restrict__ W,
        const float* __restrict__ bias,
        unsigned char* __restrict__ EF, unsigned char* __restrict__ BF,
        float* __restrict__ badj, double* __restrict__ pTrue)
{
    const int blk = blockIdx.x, tid = threadIdx.x;
    const int wave = tid >> 6, lane = tid & 63;

    if (blk < 1024) {
        float tsum = 0.0f;
        #pragma unroll
        for (int i = 0; i < 4; ++i) {
            int b = (blk * 4 + wave) + 4096 * i;
            int label = tgt[b];
            float4 e  = ((const float4*)(E + (size_t)b * EMBED))[lane];
            float4 wv = ((const float4*)(W + (size_t)label * EMBED))[lane];
            int pk = pk4_fp8(e.x, e.y, e.z, e.w);
            // k = lane*4
            *(int*)(EF + ((b >> 4) * 4096 + (lane >> 5) * 2048
                          + ((lane >> 2) & 1) * 1024
                          + ((b & 15) + ((lane >> 3) & 3) * 16) * 16
                          + (lane & 3) * 4)) = pk;
            float d = e.x * wv.x + e.y * wv.y + e.z * wv.z + e.w * wv.w;
            #pragma unroll
            for (int off = 32; off > 0; off >>= 1) d += __shfl_down(d, off, 64);
            if (lane == 0) {
                float tl = d + bias[label] - log_expected_count(label);
                tsum += softplus_f(-tl);
            }
        }
        __shared__ float ts[4];
        if (lane == 0) ts[wave] = tsum;
        __syncthreads();
        if (tid == 0) pTrue[blk] = (double)((ts[0] + ts[1]) + (ts[2] + ts[3]));
    } else {
        #pragma unroll
        for (int i = 0; i < 4; ++i) {
            int task = (blk - 1024) * 256 + tid + 16384 * i;
            int s = task >> 4, p = task & 15;   // p = 16B chunk, k = p*16
            int sid = sids[s];
            const float4* wr = (const float4*)(W + (size_t)sid * EMBED + p * 16);
            float4 w0 = wr[0], w1 = wr[1], w2 = wr[2], w3 = wr[3];
            int4 o;
            o.x = pk4_fp8(w0.x * 16.0f, w0.y * 16.0f, w0.z * 16.0f, w0.w * 16.0f);
            o.y = pk4_fp8(w1.x * 16.0f, w1.y * 16.0f, w1.z * 16.0f, w1.w * 16.0f);
            o.z = pk4_fp8(w2.x * 16.0f, w2.y * 16.0f, w2.z * 16.0f, w2.w * 16.0f);
            o.w = pk4_fp8(w3.x * 16.0f, w3.y * 16.0f, w3.z * 16.0f, w3.w * 16.0f);
            *(int4*)(BF + ((s >> 4) * 4096 + (p >> 3) * 2048 + (p & 1) * 1024
                           + ((s & 15) + ((p >> 1) & 3) * 16) * 16)) = o;
            if (p == 0) badj[s] = bias[sid] - log_expected_count(sid);
        }
    }
}

// GEMM: MX-fp8 16x16x128, LDS-staged 128x256 A-tile + 128x256 B-tile (64 KB),
// identity contiguous copy via global_load_lds; one barrier; 2x2 waves of 64x64.
// B's 1/16 unscale is done in-HW via the MX B-scale (E8M0 0x7B = 2^-4, exact).
__global__ __launch_bounds__(256, 2) void k_gemm(
        const unsigned char* __restrict__ EF,
        const unsigned char* __restrict__ BF,
        const float* __restrict__ badj,
        double* __restrict__ pGemm)
{
    __shared__ __align__(16) unsigned char As[32768];
    __shared__ __align__(16) unsigned char Bs[32768];

    const int tid  = threadIdx.x;
    const int wave = tid >> 6;
    const int lane = tid & 63;

    // Stage both tiles: 16 x 4KB contiguous chunks, wave-uniform base + lane*16
    {
        const unsigned char* gA = EF + (size_t)blockIdx.y * 32768 + wave * 1024 + lane * 16;
        const unsigned char* gB = BF + (size_t)blockIdx.x * 32768 + wave * 1024 + lane * 16;
        unsigned char* lA = As + wave * 1024 + lane * 16;
        unsigned char* lB = Bs + wave * 1024 + lane * 16;
        #pragma unroll
        for (int i = 0; i < 8; ++i) {
            __builtin_amdgcn_global_load_lds((g_void_t*)(gA + i * 4096),
                                             (lds_void_t*)(lA + i * 4096), 16, 0, 0);
            __builtin_amdgcn_global_load_lds((g_void_t*)(gB + i * 4096),
                                             (lds_void_t*)(lB + i * 4096), 16, 0, 0);
        }
    }
    asm volatile("s_waitcnt vmcnt(0)" ::: "memory");
    __syncthreads();

    const int wm = (wave >> 1) * 4;  // local A row-group base
    const int wn = (wave & 1) * 4;   // local B row-group base

    i32x8 af[2][4], bf[2][4];
    #pragma unroll
    for (int s = 0; s < 2; ++s) {
        #pragma unroll
        for (int g = 0; g < 4; ++g) {
            const unsigned char* pa = As + (wm + g) * 4096 + s * 2048 + lane * 16;
            i32x4 alo = *(const i32x4*)pa;
            i32x4 ahi = *(const i32x4*)(pa + 1024);
            af[s][g] = __builtin_shufflevector(alo, ahi, 0, 1, 2, 3, 4, 5, 6, 7);
            const unsigned char* pb = Bs + (wn + g) * 4096 + s * 2048 + lane * 16;
            i32x4 blo = *(const i32x4*)pb;
            i32x4 bhi = *(const i32x4*)(pb + 1024);
            bf[s][g] = __builtin_shufflevector(blo, bhi, 0, 1, 2, 3, 4, 5, 6, 7);
        }
    }

    f32x4 acc[4][4] = {};
    #pragma unroll
    for (int s = 0; s < 2; ++s)
        #pragma unroll
        for (int mi = 0; mi < 4; ++mi)
            #pragma unroll
            for (int ni = 0; ni < 4; ++ni)
                acc[mi][ni] = __builtin_amdgcn_mfma_scale_f32_16x16x128_f8f6f4(
                    af[s][mi], bf[s][ni], acc[mi][ni],
                    0, 0,                 // cbsz=fp8(e4m3), blgp=fp8(e4m3)
                    0, 0x7F7F7F7F,        // scale A = 2^0
                    0, 0x7B7B7B7B);       // scale B = 2^-4 (undo W*16, exact)

    // Epilogue: logit = acc + badj[col]; C/D: col=lane&15, row=quad*4+r
    float lsum = 0.0f;
    const int r16 = lane & 15;
    const int bn0 = blockIdx.x * 128 + (wave & 1) * 64;
    #pragma unroll
    for (int ni = 0; ni < 4; ++ni) {
        float ba = badj[bn0 + ni * 16 + r16];
        #pragma unroll
        for (int mi = 0; mi < 4; ++mi)
            #pragma unroll
            for (int r = 0; r < 4; ++r)
                lsum += softplus_f(acc[mi][ni][r] + ba);
    }
    #pragma unroll
    for (int off = 32; off > 0; off >>= 1) lsum += __shfl_down(lsum, off, 64);
    __syncthreads();                       // all LDS frag reads done; reuse As
    float* wsum = (float*)As;
    if (lane == 0) wsum[wave] = lsum;
    __syncthreads();
    if (tid == 0)
        pGemm[blockIdx.y * gridDim.x + blockIdx.x] =
            (double)((wsum[0] + wsum[1]) + (wsum[2] + wsum[3]));
}

__global__ __launch_bounds__(256) void k_final(
        const double* __restrict__ pTrue, const double* __restrict__ pGemm,
        float* __restrict__ out)
{
    const int tid = threadIdx.x, wave = tid >> 6, lane = tid & 63;
    double s = 0.0;
    for (int i = tid; i < 1024; i += 256) s += pTrue[i];
    for (int i = tid; i < 4096; i += 256) s += pGemm[i];
    #pragma unroll
    for (int off = 32; off > 0; off >>= 1) s += __shfl_down(s, off, 64);
    __shared__ double wsum[4];
    if (lane == 0) wsum[wave] = s;
    __syncthreads();
    if (tid == 0)
        out[0] = (float)(((wsum[0] + wsum[1]) + (wsum[2] + wsum[3]))
                         * (1.0 / (double)BATCH));
}

// ---------- launch ----------

extern "C" void kernel_launch(void* const* d_in, const int* in_sizes, int n_in,
                              void* d_out, int out_size, void* d_ws, size_t ws_size,
                              hipStream_t stream) {
    const float* emb  = (const float*)d_in[0];
    const int*   tgt  = (const int*)d_in[1];
    const int*   sids = (const int*)d_in[2];
    const float* W    = (const float*)d_in[3];
    const float* bias = (const float*)d_in[4];
    float* out = (float*)d_out;

    char* ws = (char*)d_ws;
    double*        pTrue = (double*)ws;                        // 1024 doubles
    double*        pGemm = (double*)(ws + 8192);               // 4096 doubles
    float*         badj  = (float*)(ws + 40960);               // 16 KB
    unsigned char* BF    = (unsigned char*)(ws + 57344);       // 1 MB
    unsigned char* EF    = (unsigned char*)(ws + 57344 + 1048576); // 4 MB

    hipLaunchKernelGGL(k_prep, dim3(1088), dim3(256), 0, stream,
                       emb, tgt, sids, W, bias, EF, BF, badj, pTrue);
    hipLaunchKernelGGL(k_gemm, dim3(NSAMP / 128, BATCH / 128), dim3(256), 0, stream,
                       EF, BF, badj, pGemm);
    hipLaunchKernelGGL(k_final, dim3(1), dim3(256), 0, stream,
                       pTrue, pGemm, out);
}

// Round 5
// 142.245 us; speedup vs baseline: 1.0426x; 1.0426x over previous
//
#include <hip/hip_runtime.h>
#include <cstdint>
#include <cstddef>

#define VOCAB 50000
#define EMBED 256
#define BATCH 16384
#define NSAMP 4096

typedef float f32x4 __attribute__((ext_vector_type(4)));
typedef int   i32x8 __attribute__((ext_vector_type(8)));

// ---------- helpers ----------

__device__ __forceinline__ float log_expected_count(int id) {
    float idf = (float)id;
    float p = log1pf(1.0f / (idf + 1.0f)) / logf((float)(VOCAB + 1));
    return __logf(-expm1f((float)NSAMP * log1pf(-p)));
}

// softplus(x) = max(x,0) + log1p(e^{-|x|}); deg-5 minimax (|err|<=1e-5)
__device__ __forceinline__ float softplus_f(float x) {
    float v = __expf(-fabsf(x));
    float p = fmaf(v, 0.03215845f, -0.13606275f);
    p = fmaf(v, p, 0.28947478f);
    p = fmaf(v, p, -0.49190896f);
    p = fmaf(v, p, 0.99949556f);
    return fmaxf(x, 0.0f) + v * p;
}

// pack 4 floats -> 4 fp8 e4m3 bytes (HW cvt, OCP on gfx950)
__device__ __forceinline__ int pk4_fp8(float a, float b, float c, float d) {
    int v = __builtin_amdgcn_cvt_pk_fp8_f32(a, b, 0, false);
    v = __builtin_amdgcn_cvt_pk_fp8_f32(c, d, v, true);
    return v;
}

// Fragment-order layout (round-3 proven) for an R x 256 fp8 matrix:
//   offset(r,k) = (r>>4)*4096 + (k>>5)*512 + (r&15)*32 + (k&31)
// Wave frag (group g, k-step s): contiguous 2KB at g*4096 + s*2048,
// per-lane 32B at +lane*32 (lane&15 = row, lane>>4 = k-quad).

// ---------- kernels ----------

// blocks [0,1024): true logits + E -> fp8 fragments (1 wave = 4 rows)
// blocks [1024,1088): gather W[sids] * 16 -> fp8 fragments + badj
__global__ __launch_bounds__(256) void k_prep(
        const float* __restrict__ E, const int* __restrict__ tgt,
        const int* __restrict__ sids, const float* __restrict__ W,
        const float* __restrict__ bias,
        unsigned char* __restrict__ EF, unsigned char* __restrict__ BF,
        float* __restrict__ badj, double* __restrict__ pTrue)
{
    const int blk = blockIdx.x, tid = threadIdx.x;
    const int wave = tid >> 6, lane = tid & 63;

    if (blk < 1024) {
        float tsum = 0.0f;
        #pragma unroll
        for (int i = 0; i < 4; ++i) {
            int b = (blk * 4 + wave) + 4096 * i;
            int label = tgt[b];
            float4 e  = ((const float4*)(E + (size_t)b * EMBED))[lane];
            float4 wv = ((const float4*)(W + (size_t)label * EMBED))[lane];
            int pk = pk4_fp8(e.x, e.y, e.z, e.w);
            *(int*)(EF + ((b >> 4) * 4096 + (lane >> 3) * 512
                          + (b & 15) * 32 + (lane & 7) * 4)) = pk;
            float d = e.x * wv.x + e.y * wv.y + e.z * wv.z + e.w * wv.w;
            #pragma unroll
            for (int off = 32; off > 0; off >>= 1) d += __shfl_down(d, off, 64);
            if (lane == 0) {
                float tl = d + bias[label] - log_expected_count(label);
                tsum += softplus_f(-tl);
            }
        }
        __shared__ float ts[4];
        if (lane == 0) ts[wave] = tsum;
        __syncthreads();
        if (tid == 0) pTrue[blk] = (double)((ts[0] + ts[1]) + (ts[2] + ts[3]));
    } else {
        #pragma unroll
        for (int i = 0; i < 4; ++i) {
            int task = (blk - 1024) * 256 + tid + 16384 * i;
            int s = task >> 4, p = task & 15;   // p = 16B chunk, k = p*16
            int sid = sids[s];
            const float4* wr = (const float4*)(W + (size_t)sid * EMBED + p * 16);
            float4 w0 = wr[0], w1 = wr[1], w2 = wr[2], w3 = wr[3];
            int4 o;
            o.x = pk4_fp8(w0.x * 16.0f, w0.y * 16.0f, w0.z * 16.0f, w0.w * 16.0f);
            o.y = pk4_fp8(w1.x * 16.0f, w1.y * 16.0f, w1.z * 16.0f, w1.w * 16.0f);
            o.z = pk4_fp8(w2.x * 16.0f, w2.y * 16.0f, w2.z * 16.0f, w2.w * 16.0f);
            o.w = pk4_fp8(w3.x * 16.0f, w3.y * 16.0f, w3.z * 16.0f, w3.w * 16.0f);
            *(int4*)(BF + ((s >> 4) * 4096 + (p >> 1) * 512
                           + (s & 15) * 32 + (p & 1) * 16)) = o;
            if (p == 0) badj[s] = bias[sid] - log_expected_count(sid);
        }
    }
}

// GEMM: direct-register MX-fp8, no LDS, A held in registers across 8 B-tiles.
// Grid 512 blocks: blockIdx>>3 = 256-row group, blockIdx&7 = 512-col group.
// Wave = 64-row x 512-col strip: load A frags once (64 VGPR), loop 8 B-tiles
// (load 16KB B frags, 32 mfma_scale, softplus epilogue into running sum).
// BF is 1 MB -> resident in every XCD L2; 4 waves/block share B lines (L1 hits).
__global__ __launch_bounds__(256, 2) void k_gemm(
        const unsigned char* __restrict__ EF,
        const unsigned char* __restrict__ BF,
        const float* __restrict__ badj,
        double* __restrict__ pGemm)
{
    const int tid  = threadIdx.x;
    const int wave = tid >> 6;
    const int lane = tid & 63;
    const int rg   = blockIdx.x >> 3;   // 256-row group (0..63)
    const int cg   = blockIdx.x & 7;    // 512-col group (0..7)
    const int ag0  = rg * 16 + wave * 4;  // A 16-row group base
    const int r16  = lane & 15;

    // A fragments: persistent across the whole strip
    i32x8 af[2][4];
    #pragma unroll
    for (int s = 0; s < 2; ++s)
        #pragma unroll
        for (int mi = 0; mi < 4; ++mi)
            af[s][mi] = *(const i32x8*)(EF + (size_t)(ag0 + mi) * 4096
                                        + s * 2048 + lane * 32);

    float lsum = 0.0f;
    #pragma unroll 1
    for (int j = 0; j < 8; ++j) {
        const int bg0 = cg * 32 + j * 4;          // B 16-row group base
        i32x8 bf[2][4];
        #pragma unroll
        for (int s = 0; s < 2; ++s)
            #pragma unroll
            for (int ni = 0; ni < 4; ++ni)
                bf[s][ni] = *(const i32x8*)(BF + (size_t)(bg0 + ni) * 4096
                                            + s * 2048 + lane * 32);

        f32x4 acc[4][4] = {};
        #pragma unroll
        for (int s = 0; s < 2; ++s)
            #pragma unroll
            for (int mi = 0; mi < 4; ++mi)
                #pragma unroll
                for (int ni = 0; ni < 4; ++ni)
                    acc[mi][ni] = __builtin_amdgcn_mfma_scale_f32_16x16x128_f8f6f4(
                        af[s][mi], bf[s][ni], acc[mi][ni],
                        0, 0,                 // cbsz=fp8(e4m3), blgp=fp8(e4m3)
                        0, 0x7F7F7F7F,        // scale A = 2^0
                        0, 0x7B7B7B7B);       // scale B = 2^-4 (undo W*16, exact)

        // Epilogue: C/D col=lane&15, row=quad*4+r; col -> badj index
        const int cbase = cg * 512 + j * 64 + r16;
        #pragma unroll
        for (int ni = 0; ni < 4; ++ni) {
            float ba = badj[cbase + ni * 16];
            #pragma unroll
            for (int mi = 0; mi < 4; ++mi)
                #pragma unroll
                for (int r = 0; r < 4; ++r)
                    lsum += softplus_f(acc[mi][ni][r] + ba);
        }
    }

    #pragma unroll
    for (int off = 32; off > 0; off >>= 1) lsum += __shfl_down(lsum, off, 64);
    __shared__ float wsum[4];
    if (lane == 0) wsum[wave] = lsum;
    __syncthreads();
    if (tid == 0)
        pGemm[blockIdx.x] = (double)((wsum[0] + wsum[1]) + (wsum[2] + wsum[3]));
}

__global__ __launch_bounds__(256) void k_final(
        const double* __restrict__ pTrue, const double* __restrict__ pGemm,
        float* __restrict__ out)
{
    const int tid = threadIdx.x, wave = tid >> 6, lane = tid & 63;
    double s = 0.0;
    for (int i = tid; i < 1024; i += 256) s += pTrue[i];
    for (int i = tid; i < 512; i += 256) s += pGemm[i];
    #pragma unroll
    for (int off = 32; off > 0; off >>= 1) s += __shfl_down(s, off, 64);
    __shared__ double wsum[4];
    if (lane == 0) wsum[wave] = s;
    __syncthreads();
    if (tid == 0)
        out[0] = (float)(((wsum[0] + wsum[1]) + (wsum[2] + wsum[3]))
                         * (1.0 / (double)BATCH));
}

// ---------- launch ----------

extern "C" void kernel_launch(void* const* d_in, const int* in_sizes, int n_in,
                              void* d_out, int out_size, void* d_ws, size_t ws_size,
                              hipStream_t stream) {
    const float* emb  = (const float*)d_in[0];
    const int*   tgt  = (const int*)d_in[1];
    const int*   sids = (const int*)d_in[2];
    const float* W    = (const float*)d_in[3];
    const float* bias = (const float*)d_in[4];
    float* out = (float*)d_out;

    char* ws = (char*)d_ws;
    double*        pTrue = (double*)ws;                        // 1024 doubles
    double*        pGemm = (double*)(ws + 8192);               // 512 doubles
    float*         badj  = (float*)(ws + 40960);               // 16 KB
    unsigned char* BF    = (unsigned char*)(ws + 57344);       // 1 MB
    unsigned char* EF    = (unsigned char*)(ws + 57344 + 1048576); // 4 MB

    hipLaunchKernelGGL(k_prep, dim3(1088), dim3(256), 0, stream,
                       emb, tgt, sids, W, bias, EF, BF, badj, pTrue);
    hipLaunchKernelGGL(k_gemm, dim3(512), dim3(256), 0, stream,
                       EF, BF, badj, pGemm);
    hipLaunchKernelGGL(k_final, dim3(1), dim3(256), 0, stream,
                       pTrue, pGemm, out);
}